// Round 13
// baseline (86.568 us; speedup 1.0000x reference)
//
#include <hip/hip_runtime.h>
#include <math.h>

#define BB 8
#define TT 2048
#define NE 1024
#define HH 64
#define BT (BB * TT)

typedef __attribute__((ext_vector_type(8))) short s8v;   // 8 x bf16 fragment
typedef __attribute__((ext_vector_type(4))) float f4v;   // 4 x f32 accum

__device__ inline unsigned short f2bf(float f) {
  union { float f; unsigned u; } v;
  v.f = f;
  unsigned r = (v.u + 0x7FFFu + ((v.u >> 16) & 1u)) >> 16;  // RNE
  return (unsigned short)r;
}

__device__ inline unsigned short f2bf_trunc(float f) {
  union { float f; unsigned u; } v;
  v.f = f;
  return (unsigned short)(v.u >> 16);
}

// packed f32x2 -> bf16x2 (RNE), src0 -> low16, src1 -> high16
__device__ inline unsigned cvtpk(float lo, float hi) {
  unsigned r;
  asm("v_cvt_pk_bf16_f32 %0, %1, %2" : "=v"(r) : "v"(lo), "v"(hi));
  return r;
}

// async global->LDS, 16B per lane; l is the wave-uniform base (HW adds lane*16)
__device__ inline void glds16(const unsigned short* g, unsigned short* l) {
  __builtin_amdgcn_global_load_lds(
      (const __attribute__((address_space(1))) unsigned*)g,
      (__attribute__((address_space(3))) unsigned*)l, 16, 0, 0);
}

// ---------------------------------------------------------------------------
// Kernel 0: W [1024][64] f32 x3 -> WTf, FRAGMENT-MAJOR bf16:
//   WTf[((cb*32 + ks)*64 + lane)*8 + j] = W_m[n][h],
//   cb=colblock 0..11 (col=cb*16+lr, m=col>>6, h=col&63),
//   ks=0..31 (32-wide k-slice), lane=lg*16+lr, n=ks*32+lg*8+j.
// ---------------------------------------------------------------------------
__global__ __launch_bounds__(256) void conv_wt_kernel(
    const float* __restrict__ Wq, const float* __restrict__ Wk,
    const float* __restrict__ Wv, unsigned short* __restrict__ WTf) {
  const int idx = blockIdx.x * 256 + threadIdx.x;  // 0..24575
  const int cb = idx >> 11;
  const int ks = (idx >> 6) & 31;
  const int lane = idx & 63;
  const int lr = lane & 15, lg = lane >> 4;
  const int col = cb * 16 + lr;
  const int m = col >> 6, h = col & 63;
  const int n0 = ks * 32 + lg * 8;
  const float* W = (m == 0) ? Wq : (m == 1) ? Wk : Wv;
  unsigned short v[8];
#pragma unroll
  for (int j = 0; j < 8; ++j) v[j] = f2bf(W[(size_t)(n0 + j) * HH + h]);
  *reinterpret_cast<uint4*>(WTf + (size_t)idx * 8) =
      *reinterpret_cast<const uint4*>(v);
}

// ---------------------------------------------------------------------------
// Kernel 1: QKV projection — LDS+glds pipeline with COUNTED-vmcnt barriers.
//   (unchanged — T3/T4 confirmed, ~25 µs)
// ---------------------------------------------------------------------------
__global__ __launch_bounds__(256, 5) void qkv_proj_mfma(
    const float* __restrict__ x, const unsigned short* __restrict__ WTf,
    unsigned short* __restrict__ Q, unsigned short* __restrict__ K,
    unsigned short* __restrict__ VT) {
  __shared__ __align__(16) unsigned short Bbuf[2][6144];  // 12 KB each
  __shared__ __align__(16) unsigned short Abuf[3][640];   // [16][40] bf16 each

  const int tid = threadIdx.x;
  const int lane = tid & 63;
  const int w = tid >> 6;
  const int lr = lane & 15, lg = lane >> 4;
  const int row0 = blockIdx.x * 16;

  const int arow = tid >> 4, aunit = tid & 15;  // A-stage: row 0..15, 2-float unit
  const float* __restrict__ xsrc = x + (size_t)(row0 + arow) * NE + aunit * 2;

  f4v acc[3];
#pragma unroll
  for (int c = 0; c < 3; ++c) acc[c] = (f4v)0.f;

  float2 La[2];  // A global-prefetch ring (data for tile t+2, t+3)

  auto ISSUE_B = [&](int buf, int t) {
#pragma unroll
    for (int j = 0; j < 3; ++j) {
      const int cb = w * 3 + j;
      glds16(WTf + (size_t)(cb * 32 + t) * 512 + lane * 8, &Bbuf[buf][cb * 512]);
    }
  };

  // ---- prologue: A(0),A(1) -> LDS; B(0) glds; A(2) in flight
  La[0] = *reinterpret_cast<const float2*>(xsrc);
  La[1] = *reinterpret_cast<const float2*>(xsrc + 32);
  ISSUE_B(0, 0);
  *reinterpret_cast<unsigned*>(&Abuf[0][arow * 40 + aunit * 2]) =
      cvtpk(La[0].x, La[0].y);
  La[0] = *reinterpret_cast<const float2*>(xsrc + 2 * 32);
  *reinterpret_cast<unsigned*>(&Abuf[1][arow * 40 + aunit * 2]) =
      cvtpk(La[1].x, La[1].y);
  asm volatile("s_waitcnt vmcnt(1) lgkmcnt(0)" ::: "memory");
  __builtin_amdgcn_s_barrier();
  __builtin_amdgcn_sched_barrier(0);

#pragma unroll
  for (int t = 0; t < 32; ++t) {
    const int cur = t & 1;
    if (t + 1 < 32) ISSUE_B(cur ^ 1, t + 1);      // B for next tile (L2)
    __builtin_amdgcn_sched_barrier(0);
    if (t + 3 < 32)                                // A for tile t+3 (HBM)
      La[(t + 3) & 1] = *reinterpret_cast<const float2*>(xsrc + (t + 3) * 32);
    __builtin_amdgcn_sched_barrier(0);
    // ---- compute tile t
    const s8v a = *reinterpret_cast<const s8v*>(&Abuf[t % 3][lr * 40 + lg * 8]);
#pragma unroll
    for (int j = 0; j < 3; ++j) {
      const int cb = w * 3 + j;
      const s8v b = *reinterpret_cast<const s8v*>(&Bbuf[cur][cb * 512 + lane * 8]);
      acc[j] = __builtin_amdgcn_mfma_f32_16x16x32_bf16(a, b, acc[j], 0, 0, 0);
    }
    if (t + 2 < 32)  // write A(t+2) to its LDS slot (loaded at tile t-1)
      *reinterpret_cast<unsigned*>(&Abuf[(t + 2) % 3][arow * 40 + aunit * 2]) =
          cvtpk(La[t & 1].x, La[t & 1].y);
    if (t + 1 < 32) {
      if (t + 3 < 32) {  // newest load = A(t+3): keep it flying across barrier
        asm volatile("s_waitcnt vmcnt(1) lgkmcnt(0)" ::: "memory");
      } else {           // tail: no A in flight -> full drain
        asm volatile("s_waitcnt vmcnt(0) lgkmcnt(0)" ::: "memory");
      }
      __builtin_amdgcn_s_barrier();
      __builtin_amdgcn_sched_barrier(0);
    }
  }

  // ---- epilogue (Q pre-scaled into log2-softmax domain)
  const float QSCL = 0.18033688011112042f;  // 0.125 * log2(e)
#pragma unroll
  for (int c = 0; c < 3; ++c) {
    const int col = (w * 3 + c) * 16 + lr;
    const int m = col >> 6;  // uniform per (w,c)
    const int h = col & 63;
#pragma unroll
    for (int r = 0; r < 4; ++r) {
      const int rr = row0 + lg * 4 + r;  // D: row=(lane>>4)*4+reg
      if (m == 0) {
        Q[(size_t)rr * HH + h] = f2bf(acc[c][r] * QSCL);
      } else if (m == 1) {
        K[(size_t)rr * HH + h] = f2bf(acc[c][r]);
      } else {
        const int bb2 = rr >> 11, tt2 = rr & (TT - 1);
        VT[((size_t)bb2 * HH + h) * TT + tt2] = f2bf(acc[c][r]);
      }
    }
  }
}

// ---------------------------------------------------------------------------
// Kernel 2: causal flash attention, in-block split-k.  1024 blocks x 4 waves.
//   Round-13: SHUFFLE-FREE fast path.  Each lane bounds its OWN 16 scores
//   (pure VALU max3 chain); if __all(local growth <= 8) then P = exp2(s-m_old)
//   is provably <= 2^8 for the whole row -> NO cross-lane reduce, NO rescale.
//   Slow path (first tile: m=-inf -> NaN/inf fails <=, rare growth) does the
//   full 16-lane shfl reduce + rescale.  V restored to all-8-upfront (r12's
//   per-kh split exposed L2 latency before PV kh1).  K WAR-prefetch,
//   ones-MFMA row-sum, LPT, setprio kept.
// ---------------------------------------------------------------------------
__global__ __launch_bounds__(256, 4) void flash_attn_mfma(
    const unsigned short* __restrict__ Q, const unsigned short* __restrict__ K,
    const unsigned short* __restrict__ VT, float* __restrict__ out) {
  __shared__ unsigned short pl[4][16][72];
  __shared__ float ol[4][16][64];
  __shared__ float ml[4][16];
  __shared__ float ll[4][16];

  const int tid = threadIdx.x;
  const int lane = tid & 63;
  const int w = tid >> 6;
  const int lr = lane & 15;
  const int lg = lane >> 4;
  const int bid = blockIdx.x;
  const int b = bid & 7;
  const int qt = 127 - (bid >> 3);  // LPT: longest q-tiles dispatched first
  const int q0 = qt * 16;
  const size_t rowbase = (size_t)b * TT;

  const int nt = (qt >> 2) + 1;     // k-tiles of 64 covering rows < q0+16
  const int base = nt >> 2, rem = nt & 3;
  const int t0 = w * base + (w < rem ? w : rem);
  const int kend = t0 + base + (w < rem ? 1 : 0);

  const s8v qf0 = *reinterpret_cast<const s8v*>(
      Q + (rowbase + q0 + lr) * HH + lg * 8);
  const s8v qf1 = *reinterpret_cast<const s8v*>(
      Q + (rowbase + q0 + lr) * HH + 32 + lg * 8);

  s8v vone;
#pragma unroll
  for (int j = 0; j < 8; ++j) vone[j] = (short)0x3F80;  // bf16 1.0

  f4v o[5];  // o[4] = row-sum column (l)
#pragma unroll
  for (int n = 0; n < 5; ++n) o[n] = (f4v)0.f;
  float mrow[4];
#pragma unroll
  for (int r = 0; r < 4; ++r) mrow[r] = -INFINITY;

  const unsigned short* const Kb = K + rowbase * HH;
  const unsigned short* const Vb = VT + (size_t)b * HH * TT;

  s8v kf[2][4];  // single buffer: reloaded in place after each QK cluster
  auto LOADK = [&](int kt) {
    const int k0 = kt * 64;
#pragma unroll
    for (int nk = 0; nk < 4; ++nk) {
      const unsigned short* kp = Kb + (size_t)(k0 + 16 * nk + lr) * HH + lg * 8;
      kf[0][nk] = *reinterpret_cast<const s8v*>(kp);
      kf[1][nk] = *reinterpret_cast<const s8v*>(kp + 32);
    }
  };

  if (t0 < kend) LOADK(t0);
  for (int kt = t0; kt < kend; ++kt) {
    const int k0 = kt * 64;
    f4v s[4];
#pragma unroll
    for (int nk = 0; nk < 4; ++nk) s[nk] = (f4v)0.f;
    __builtin_amdgcn_s_setprio(1);
#pragma unroll
    for (int nk = 0; nk < 4; ++nk) {
      s[nk] = __builtin_amdgcn_mfma_f32_16x16x32_bf16(qf0, kf[0][nk], s[nk], 0, 0, 0);
      s[nk] = __builtin_amdgcn_mfma_f32_16x16x32_bf16(qf1, kf[1][nk], s[nk], 0, 0, 0);
    }
    __builtin_amdgcn_s_setprio(0);
    // prefetch next tile's K into the SAME regs (WAR; flies during softmax+PV)
    if (kt + 1 < kend) LOADK(kt + 1);
    // ALL 8 V frags upfront: latency hidden under softmax (r8 pattern)
    s8v vfr[2][4];
#pragma unroll
    for (int kh = 0; kh < 2; ++kh)
#pragma unroll
      for (int n = 0; n < 4; ++n)
        vfr[kh][n] = *reinterpret_cast<const s8v*>(
            Vb + (size_t)(16 * n + lr) * TT + k0 + kh * 32 + lg * 8);
    __builtin_amdgcn_sched_barrier(0);  // pin loads above the softmax VALU

    // scores already log2-domain (Q pre-scaled); mask only on diag tile
    if (kt == nt - 1) {
#pragma unroll
      for (int nk = 0; nk < 4; ++nk) {
        const int kk = k0 + 16 * nk + lr;
#pragma unroll
        for (int r = 0; r < 4; ++r) {
          const int qq = q0 + lg * 4 + r;
          if (kk > qq) s[nk][r] = -INFINITY;
        }
      }
    }

    // LOCAL max of own 16 scores (pure VALU, no cross-lane)
    float lmax[4];
#pragma unroll
    for (int r = 0; r < 4; ++r)
      lmax[r] = fmaxf(fmaxf(s[0][r], s[1][r]), fmaxf(s[2][r], s[3][r]));
    // fast iff EVERY lane's growth provably <= 8  (NaN/inf -> slow, correct)
    bool ok = true;
#pragma unroll
    for (int r = 0; r < 4; ++r) ok = ok && (lmax[r] - mrow[r] <= 8.f);
    if (!__all(ok)) {
      // slow path: full 16-lane reduce + rescale (first tile, rare growth)
#pragma unroll
      for (int r = 0; r < 4; ++r) {
        float mx = lmax[r];
#pragma unroll
        for (int off = 1; off < 16; off <<= 1)
          mx = fmaxf(mx, __shfl_xor(mx, off));
        const float mnew = fmaxf(mrow[r], mx);
        const float scl = exp2f(mrow[r] - mnew);
        mrow[r] = mnew;
#pragma unroll
        for (int n = 0; n < 5; ++n) o[n][r] *= scl;
      }
    }
    // p = exp2(s - m) <= 2^8; l via ones-MFMA (no sum shuffle)
#pragma unroll
    for (int nk = 0; nk < 4; ++nk)
#pragma unroll
      for (int r = 0; r < 4; ++r)
        pl[w][lg * 4 + r][16 * nk + lr] = f2bf_trunc(exp2f(s[nk][r] - mrow[r]));

    // PV (pa/pb from per-wave LDS; no barrier needed)
#pragma unroll
    for (int kh = 0; kh < 2; ++kh) {
      const int pc = kh * 32 + lg * 8;
      const ushort4 plo = *reinterpret_cast<const ushort4*>(&pl[w][lr][pc]);
      const ushort4 phi = *reinterpret_cast<const ushort4*>(&pl[w][lr][pc + 4]);
      s8v pa;
      pa[0] = plo.x; pa[1] = plo.y; pa[2] = plo.z; pa[3] = plo.w;
      pa[4] = phi.x; pa[5] = phi.y; pa[6] = phi.z; pa[7] = phi.w;
      __builtin_amdgcn_s_setprio(1);
#pragma unroll
      for (int n = 0; n < 4; ++n)
        o[n] = __builtin_amdgcn_mfma_f32_16x16x32_bf16(pa, vfr[kh][n], o[n], 0, 0, 0);
      o[4] = __builtin_amdgcn_mfma_f32_16x16x32_bf16(pa, vone, o[4], 0, 0, 0);
      __builtin_amdgcn_s_setprio(0);
    }
  }

  // publish per-wave partials (l = o[4])
#pragma unroll
  for (int n = 0; n < 4; ++n)
#pragma unroll
    for (int r = 0; r < 4; ++r) ol[w][lg * 4 + r][16 * n + lr] = o[n][r];
  if (lr == 0) {
#pragma unroll
    for (int r = 0; r < 4; ++r) {
      ml[w][lg * 4 + r] = mrow[r];
      ll[w][lg * 4 + r] = o[4][r];
    }
  }
  __syncthreads();

  // combine: thread -> (row = tid>>4, 4 cols at (tid&15)*4)
  const int row = tid >> 4;
  const int c0 = (tid & 15) * 4;
  float m0 = ml[0][row], m1 = ml[1][row], m2 = ml[2][row], m3 = ml[3][row];
  const float ms = fmaxf(fmaxf(m0, m1), fmaxf(m2, m3));
  const float w0 = exp2f(m0 - ms), w1 = exp2f(m1 - ms);
  const float w2 = exp2f(m2 - ms), w3 = exp2f(m3 - ms);
  const float lsum = w0 * ll[0][row] + w1 * ll[1][row] +
                     w2 * ll[2][row] + w3 * ll[3][row];
  float4 osum;
  osum.x = w0 * ol[0][row][c0 + 0] + w1 * ol[1][row][c0 + 0] +
           w2 * ol[2][row][c0 + 0] + w3 * ol[3][row][c0 + 0];
  osum.y = w0 * ol[0][row][c0 + 1] + w1 * ol[1][row][c0 + 1] +
           w2 * ol[2][row][c0 + 1] + w3 * ol[3][row][c0 + 1];
  osum.z = w0 * ol[0][row][c0 + 2] + w1 * ol[1][row][c0 + 2] +
           w2 * ol[2][row][c0 + 2] + w3 * ol[3][row][c0 + 2];
  osum.w = w0 * ol[0][row][c0 + 3] + w1 * ol[1][row][c0 + 3] +
           w2 * ol[2][row][c0 + 3] + w3 * ol[3][row][c0 + 3];
  const float inv = 1.0f / lsum;
  float4 res;
  res.x = osum.x * inv; res.y = osum.y * inv;
  res.z = osum.z * inv; res.w = osum.w * inv;
  *reinterpret_cast<float4*>(out + (rowbase + q0 + row) * HH + c0) = res;
}

extern "C" void kernel_launch(void* const* d_in, const int* in_sizes, int n_in,
                              void* d_out, int out_size, void* d_ws, size_t ws_size,
                              hipStream_t stream) {
  const float* x  = (const float*)d_in[0];
  const float* Wk = (const float*)d_in[1];
  const float* Wq = (const float*)d_in[2];
  const float* Wv = (const float*)d_in[3];
  float* out = (float*)d_out;

  unsigned short* ws = (unsigned short*)d_ws;
  unsigned short* Q  = ws;                           // BT*HH bf16
  unsigned short* K  = ws + (size_t)BT * HH;         // BT*HH bf16
  unsigned short* VT = ws + 2 * (size_t)BT * HH;     // B*HH*TT bf16
  unsigned short* WT = ws + 3 * (size_t)BT * HH;     // 192*1024 bf16 (frag-major)

  conv_wt_kernel<<<96, 256, 0, stream>>>(Wq, Wk, Wv, WT);
  qkv_proj_mfma<<<1024, 256, 0, stream>>>(x, WT, Q, K, VT);
  flash_attn_mfma<<<1024, 256, 0, stream>>>(Q, K, VT, out);
}

// Round 14
// 71.305 us; speedup vs baseline: 1.2141x; 1.2141x over previous
//
#include <hip/hip_runtime.h>
#include <math.h>

#define BB 8
#define TT 2048
#define NE 1024
#define HH 64
#define BT (BB * TT)

typedef __attribute__((ext_vector_type(8))) short s8v;   // 8 x bf16 fragment
typedef __attribute__((ext_vector_type(4))) float f4v;   // 4 x f32 accum

__device__ inline unsigned short f2bf(float f) {
  union { float f; unsigned u; } v;
  v.f = f;
  unsigned r = (v.u + 0x7FFFu + ((v.u >> 16) & 1u)) >> 16;  // RNE
  return (unsigned short)r;
}

__device__ inline unsigned short f2bf_trunc(float f) {
  union { float f; unsigned u; } v;
  v.f = f;
  return (unsigned short)(v.u >> 16);
}

// packed f32x2 -> bf16x2 (RNE), src0 -> low16, src1 -> high16
__device__ inline unsigned cvtpk(float lo, float hi) {
  unsigned r;
  asm("v_cvt_pk_bf16_f32 %0, %1, %2" : "=v"(r) : "v"(lo), "v"(hi));
  return r;
}

// async global->LDS, 16B per lane; l is the wave-uniform base (HW adds lane*16)
__device__ inline void glds16(const unsigned short* g, unsigned short* l) {
  __builtin_amdgcn_global_load_lds(
      (const __attribute__((address_space(1))) unsigned*)g,
      (__attribute__((address_space(3))) unsigned*)l, 16, 0, 0);
}

// ---------------------------------------------------------------------------
// Kernel 0: W [1024][64] f32 x3 -> WTf, FRAGMENT-MAJOR bf16:
//   WTf[((cb*32 + ks)*64 + lane)*8 + j] = W_m[n][h],
//   cb=colblock 0..11 (col=cb*16+lr, m=col>>6, h=col&63),
//   ks=0..31 (32-wide k-slice), lane=lg*16+lr, n=ks*32+lg*8+j.
// ---------------------------------------------------------------------------
__global__ __launch_bounds__(256) void conv_wt_kernel(
    const float* __restrict__ Wq, const float* __restrict__ Wk,
    const float* __restrict__ Wv, unsigned short* __restrict__ WTf) {
  const int idx = blockIdx.x * 256 + threadIdx.x;  // 0..24575
  const int cb = idx >> 11;
  const int ks = (idx >> 6) & 31;
  const int lane = idx & 63;
  const int lr = lane & 15, lg = lane >> 4;
  const int col = cb * 16 + lr;
  const int m = col >> 6, h = col & 63;
  const int n0 = ks * 32 + lg * 8;
  const float* W = (m == 0) ? Wq : (m == 1) ? Wk : Wv;
  unsigned short v[8];
#pragma unroll
  for (int j = 0; j < 8; ++j) v[j] = f2bf(W[(size_t)(n0 + j) * HH + h]);
  *reinterpret_cast<uint4*>(WTf + (size_t)idx * 8) =
      *reinterpret_cast<const uint4*>(v);
}

// ---------------------------------------------------------------------------
// Kernel 1: QKV projection — LDS+glds pipeline with COUNTED-vmcnt barriers.
//   (r11 version, measured ~25 µs — T3/T4 counted-vmcnt + 5 blocks/CU)
// ---------------------------------------------------------------------------
__global__ __launch_bounds__(256, 5) void qkv_proj_mfma(
    const float* __restrict__ x, const unsigned short* __restrict__ WTf,
    unsigned short* __restrict__ Q, unsigned short* __restrict__ K,
    unsigned short* __restrict__ VT) {
  __shared__ __align__(16) unsigned short Bbuf[2][6144];  // 12 KB each
  __shared__ __align__(16) unsigned short Abuf[3][640];   // [16][40] bf16 each

  const int tid = threadIdx.x;
  const int lane = tid & 63;
  const int w = tid >> 6;
  const int lr = lane & 15, lg = lane >> 4;
  const int row0 = blockIdx.x * 16;

  const int arow = tid >> 4, aunit = tid & 15;  // A-stage: row 0..15, 2-float unit
  const float* __restrict__ xsrc = x + (size_t)(row0 + arow) * NE + aunit * 2;

  f4v acc[3];
#pragma unroll
  for (int c = 0; c < 3; ++c) acc[c] = (f4v)0.f;

  float2 La[2];  // A global-prefetch ring (data for tile t+2, t+3)

  auto ISSUE_B = [&](int buf, int t) {
#pragma unroll
    for (int j = 0; j < 3; ++j) {
      const int cb = w * 3 + j;
      glds16(WTf + (size_t)(cb * 32 + t) * 512 + lane * 8, &Bbuf[buf][cb * 512]);
    }
  };

  // ---- prologue: A(0),A(1) -> LDS; B(0) glds; A(2) in flight
  La[0] = *reinterpret_cast<const float2*>(xsrc);
  La[1] = *reinterpret_cast<const float2*>(xsrc + 32);
  ISSUE_B(0, 0);
  *reinterpret_cast<unsigned*>(&Abuf[0][arow * 40 + aunit * 2]) =
      cvtpk(La[0].x, La[0].y);
  La[0] = *reinterpret_cast<const float2*>(xsrc + 2 * 32);
  *reinterpret_cast<unsigned*>(&Abuf[1][arow * 40 + aunit * 2]) =
      cvtpk(La[1].x, La[1].y);
  asm volatile("s_waitcnt vmcnt(1) lgkmcnt(0)" ::: "memory");
  __builtin_amdgcn_s_barrier();
  __builtin_amdgcn_sched_barrier(0);

#pragma unroll
  for (int t = 0; t < 32; ++t) {
    const int cur = t & 1;
    if (t + 1 < 32) ISSUE_B(cur ^ 1, t + 1);      // B for next tile (L2)
    __builtin_amdgcn_sched_barrier(0);
    if (t + 3 < 32)                                // A for tile t+3 (HBM)
      La[(t + 3) & 1] = *reinterpret_cast<const float2*>(xsrc + (t + 3) * 32);
    __builtin_amdgcn_sched_barrier(0);
    // ---- compute tile t
    const s8v a = *reinterpret_cast<const s8v*>(&Abuf[t % 3][lr * 40 + lg * 8]);
#pragma unroll
    for (int j = 0; j < 3; ++j) {
      const int cb = w * 3 + j;
      const s8v b = *reinterpret_cast<const s8v*>(&Bbuf[cur][cb * 512 + lane * 8]);
      acc[j] = __builtin_amdgcn_mfma_f32_16x16x32_bf16(a, b, acc[j], 0, 0, 0);
    }
    if (t + 2 < 32)  // write A(t+2) to its LDS slot (loaded at tile t-1)
      *reinterpret_cast<unsigned*>(&Abuf[(t + 2) % 3][arow * 40 + aunit * 2]) =
          cvtpk(La[t & 1].x, La[t & 1].y);
    if (t + 1 < 32) {
      if (t + 3 < 32) {  // newest load = A(t+3): keep it flying across barrier
        asm volatile("s_waitcnt vmcnt(1) lgkmcnt(0)" ::: "memory");
      } else {           // tail: no A in flight -> full drain
        asm volatile("s_waitcnt vmcnt(0) lgkmcnt(0)" ::: "memory");
      }
      __builtin_amdgcn_s_barrier();
      __builtin_amdgcn_sched_barrier(0);
    }
  }

  // ---- epilogue (Q pre-scaled into log2-softmax domain)
  const float QSCL = 0.18033688011112042f;  // 0.125 * log2(e)
#pragma unroll
  for (int c = 0; c < 3; ++c) {
    const int col = (w * 3 + c) * 16 + lr;
    const int m = col >> 6;  // uniform per (w,c)
    const int h = col & 63;
#pragma unroll
    for (int r = 0; r < 4; ++r) {
      const int rr = row0 + lg * 4 + r;  // D: row=(lane>>4)*4+reg
      if (m == 0) {
        Q[(size_t)rr * HH + h] = f2bf(acc[c][r] * QSCL);
      } else if (m == 1) {
        K[(size_t)rr * HH + h] = f2bf(acc[c][r]);
      } else {
        const int bb2 = rr >> 11, tt2 = rr & (TT - 1);
        VT[((size_t)bb2 * HH + h) * TT + tt2] = f2bf(acc[c][r]);
      }
    }
  }
}

// ---------------------------------------------------------------------------
// Kernel 2: causal flash attention — r7 version VERBATIM (measured best:
//   41.8 µs, VGPR 64, no spill).  In-block split-k, LPT dispatch, Q
//   pre-scaled, defer-max (shuffle reduce kept, rescale skipped when growth
//   <= 8), shuffle row-sum, V x8 upfront, setprio around MFMA clusters.
//   LESSON (r8-r13): K-prefetch/ones-MFMA/V-split variants all spill or
//   expose latency — do not re-add without a structural VGPR plan.
// ---------------------------------------------------------------------------
__global__ __launch_bounds__(256, 4) void flash_attn_mfma(
    const unsigned short* __restrict__ Q, const unsigned short* __restrict__ K,
    const unsigned short* __restrict__ VT, float* __restrict__ out) {
  __shared__ unsigned short pl[4][16][72];
  __shared__ float ol[4][16][64];
  __shared__ float ml[4][16];
  __shared__ float ll[4][16];

  const int tid = threadIdx.x;
  const int lane = tid & 63;
  const int w = tid >> 6;
  const int lr = lane & 15;
  const int lg = lane >> 4;
  const int bid = blockIdx.x;
  const int b = bid & 7;
  const int qt = 127 - (bid >> 3);  // LPT: longest q-tiles dispatched first
  const int q0 = qt * 16;
  const size_t rowbase = (size_t)b * TT;

  const int nt = (qt >> 2) + 1;     // k-tiles of 64 covering rows < q0+16
  const int base = nt >> 2, rem = nt & 3;
  const int t0 = w * base + (w < rem ? w : rem);
  const int cnt = base + (w < rem ? 1 : 0);

  const s8v qf0 = *reinterpret_cast<const s8v*>(
      Q + (rowbase + q0 + lr) * HH + lg * 8);
  const s8v qf1 = *reinterpret_cast<const s8v*>(
      Q + (rowbase + q0 + lr) * HH + 32 + lg * 8);

  f4v o[4];
#pragma unroll
  for (int n = 0; n < 4; ++n) o[n] = (f4v)0.f;
  float mrow[4], lrow[4];
#pragma unroll
  for (int r = 0; r < 4; ++r) { mrow[r] = -INFINITY; lrow[r] = 0.f; }

  for (int kt = t0; kt < t0 + cnt; ++kt) {
    const int k0 = kt * 64;
    f4v s[4];
#pragma unroll
    for (int nk = 0; nk < 4; ++nk) s[nk] = (f4v)0.f;
    __builtin_amdgcn_s_setprio(1);
#pragma unroll
    for (int nk = 0; nk < 4; ++nk) {
      const unsigned short* kp = K + (rowbase + k0 + 16 * nk + lr) * HH + lg * 8;
      const s8v kf0 = *reinterpret_cast<const s8v*>(kp);
      const s8v kf1 = *reinterpret_cast<const s8v*>(kp + 32);
      s[nk] = __builtin_amdgcn_mfma_f32_16x16x32_bf16(qf0, kf0, s[nk], 0, 0, 0);
      s[nk] = __builtin_amdgcn_mfma_f32_16x16x32_bf16(qf1, kf1, s[nk], 0, 0, 0);
    }
    __builtin_amdgcn_s_setprio(0);
    // hoist V loads: L2 latency hides under softmax
    s8v vfr[2][4];
#pragma unroll
    for (int kh = 0; kh < 2; ++kh)
#pragma unroll
      for (int n = 0; n < 4; ++n)
        vfr[kh][n] = *reinterpret_cast<const s8v*>(
            VT + ((size_t)b * HH + 16 * n + lr) * TT + k0 + kh * 32 + lg * 8);

    // scores are already log2-domain (Q pre-scaled); only mask on diag tile
    if (kt == nt - 1) {
#pragma unroll
      for (int nk = 0; nk < 4; ++nk) {
        const int kk = k0 + 16 * nk + lr;
#pragma unroll
        for (int r = 0; r < 4; ++r) {
          const int qq = q0 + lg * 4 + r;
          if (kk > qq) s[nk][r] = -INFINITY;
        }
      }
    }

    // row max (16-lane reduce) + T13 defer-max decision
    float mx_[4];
    float grow = -INFINITY;
#pragma unroll
    for (int r = 0; r < 4; ++r) {
      float mx = fmaxf(fmaxf(s[0][r], s[1][r]), fmaxf(s[2][r], s[3][r]));
#pragma unroll
      for (int off = 1; off < 16; off <<= 1)
        mx = fmaxf(mx, __shfl_xor(mx, off));
      mx_[r] = mx;
      grow = fmaxf(grow, mx - mrow[r]);
    }
    if (!__all(grow <= 8.f)) {  // wave-uniform rescale (rare after warmup)
#pragma unroll
      for (int r = 0; r < 4; ++r) {
        const float mnew = fmaxf(mrow[r], mx_[r]);
        const float scl = exp2f(mrow[r] - mnew);
        mrow[r] = mnew;
        lrow[r] *= scl;
#pragma unroll
        for (int n = 0; n < 4; ++n) o[n][r] *= scl;
      }
    }
    // p = exp2(s - m) (m possibly deferred; p bounded by 2^8), row-sum
#pragma unroll
    for (int r = 0; r < 4; ++r) {
      float rs = 0.f;
#pragma unroll
      for (int nk = 0; nk < 4; ++nk) {
        const float p = exp2f(s[nk][r] - mrow[r]);
        s[nk][r] = p;
        rs += p;
      }
#pragma unroll
      for (int off = 1; off < 16; off <<= 1)
        rs += __shfl_xor(rs, off);
      lrow[r] += rs;
    }
    // P: D-layout -> per-wave LDS (no barrier needed)
#pragma unroll
    for (int nk = 0; nk < 4; ++nk)
#pragma unroll
      for (int r = 0; r < 4; ++r)
        pl[w][lg * 4 + r][16 * nk + lr] = f2bf_trunc(s[nk][r]);
    // PV
#pragma unroll
    for (int kh = 0; kh < 2; ++kh) {
      const int pc = kh * 32 + lg * 8;
      const ushort4 plo = *reinterpret_cast<const ushort4*>(&pl[w][lr][pc]);
      const ushort4 phi = *reinterpret_cast<const ushort4*>(&pl[w][lr][pc + 4]);
      s8v pa;
      pa[0] = plo.x; pa[1] = plo.y; pa[2] = plo.z; pa[3] = plo.w;
      pa[4] = phi.x; pa[5] = phi.y; pa[6] = phi.z; pa[7] = phi.w;
      __builtin_amdgcn_s_setprio(1);
#pragma unroll
      for (int n = 0; n < 4; ++n)
        o[n] = __builtin_amdgcn_mfma_f32_16x16x32_bf16(pa, vfr[kh][n], o[n], 0, 0, 0);
      __builtin_amdgcn_s_setprio(0);
    }
  }

  // publish per-wave partials
#pragma unroll
  for (int n = 0; n < 4; ++n)
#pragma unroll
    for (int r = 0; r < 4; ++r) ol[w][lg * 4 + r][16 * n + lr] = o[n][r];
  if (lr == 0) {
#pragma unroll
    for (int r = 0; r < 4; ++r) {
      ml[w][lg * 4 + r] = mrow[r];
      ll[w][lg * 4 + r] = lrow[r];
    }
  }
  __syncthreads();

  // combine: thread -> (row = tid>>4, 4 cols at (tid&15)*4)
  const int row = tid >> 4;
  const int c0 = (tid & 15) * 4;
  float m0 = ml[0][row], m1 = ml[1][row], m2 = ml[2][row], m3 = ml[3][row];
  const float ms = fmaxf(fmaxf(m0, m1), fmaxf(m2, m3));
  const float w0 = exp2f(m0 - ms), w1 = exp2f(m1 - ms);
  const float w2 = exp2f(m2 - ms), w3 = exp2f(m3 - ms);
  const float lsum = w0 * ll[0][row] + w1 * ll[1][row] +
                     w2 * ll[2][row] + w3 * ll[3][row];
  float4 osum;
  osum.x = w0 * ol[0][row][c0 + 0] + w1 * ol[1][row][c0 + 0] +
           w2 * ol[2][row][c0 + 0] + w3 * ol[3][row][c0 + 0];
  osum.y = w0 * ol[0][row][c0 + 1] + w1 * ol[1][row][c0 + 1] +
           w2 * ol[2][row][c0 + 1] + w3 * ol[3][row][c0 + 1];
  osum.z = w0 * ol[0][row][c0 + 2] + w1 * ol[1][row][c0 + 2] +
           w2 * ol[2][row][c0 + 2] + w3 * ol[3][row][c0 + 2];
  osum.w = w0 * ol[0][row][c0 + 3] + w1 * ol[1][row][c0 + 3] +
           w2 * ol[2][row][c0 + 3] + w3 * ol[3][row][c0 + 3];
  const float inv = 1.0f / lsum;
  float4 res;
  res.x = osum.x * inv; res.y = osum.y * inv;
  res.z = osum.z * inv; res.w = osum.w * inv;
  *reinterpret_cast<float4*>(out + (rowbase + q0 + row) * HH + c0) = res;
}

extern "C" void kernel_launch(void* const* d_in, const int* in_sizes, int n_in,
                              void* d_out, int out_size, void* d_ws, size_t ws_size,
                              hipStream_t stream) {
  const float* x  = (const float*)d_in[0];
  const float* Wk = (const float*)d_in[1];
  const float* Wq = (const float*)d_in[2];
  const float* Wv = (const float*)d_in[3];
  float* out = (float*)d_out;

  unsigned short* ws = (unsigned short*)d_ws;
  unsigned short* Q  = ws;                           // BT*HH bf16
  unsigned short* K  = ws + (size_t)BT * HH;         // BT*HH bf16
  unsigned short* VT = ws + 2 * (size_t)BT * HH;     // B*HH*TT bf16
  unsigned short* WT = ws + 3 * (size_t)BT * HH;     // 192*1024 bf16 (frag-major)

  conv_wt_kernel<<<96, 256, 0, stream>>>(Wq, Wk, Wv, WT);
  qkv_proj_mfma<<<1024, 256, 0, stream>>>(x, WT, Q, K, VT);
  flash_attn_mfma<<<1024, 256, 0, stream>>>(Q, K, VT, out);
}